// Round 8
// baseline (435.445 us; speedup 1.0000x reference)
//
#include <hip/hip_runtime.h>

// Spiking self-attention (Spikformer SSA) forward — MFMA GEMM (256x128 qkv /
// 128x128 proj tiles) with BN stats fused into the GEMM epilogue (per-block
// fp64 partials, deterministic reduce). global_load_lds staging w/ pre-swizzled
// source + bijective XCD-chunked grid swizzle. T=16,B=8,N=196,C=512,H=8,hd=64.

#define TT 16
#define BB 8
#define NNQ 196
#define CC 512
#define HH 8
#define HD 64
#define O3 1536
#define BN (BB*NNQ)          // 1568
#define PT (BN*CC)           // 802816
#define WTOT ((O3+CC)*CC)    // 1048576 split-weight elems

static constexpr float VTH = 0.5f;
typedef __attribute__((ext_vector_type(8))) short short8;
typedef __attribute__((ext_vector_type(4))) float f32x4;
typedef unsigned short u16;

__device__ __forceinline__ float sigm(float w){ return 1.f/(1.f+expf(-w)); }

__device__ __forceinline__ float lif_step(float x, float& v, float sg){
  float d  = __fsub_rn(x, v);
  float dd = __fmul_rn(d, sg);
  v = __fadd_rn(v, dd);
  float sp = (v >= VTH) ? 1.f : 0.f;
  v = __fmul_rn(v, __fsub_rn(1.f, sp));
  return sp;
}

__device__ __forceinline__ u16 bf16_rn(float x){
  unsigned u = __float_as_uint(x);
  unsigned r = u + 0x7FFF + ((u>>16)&1);
  return (u16)(r>>16);
}
__device__ __forceinline__ float bf16_to_f(u16 h){
  return __uint_as_float(((unsigned)h)<<16);
}

__device__ __forceinline__ void gld_lds16(const void* g, void* l){
  __builtin_amdgcn_global_load_lds(
    (const __attribute__((address_space(1))) unsigned int*)g,
    (__attribute__((address_space(3))) unsigned int*)l, 16, 0, 0);
}

// ---- split weights into hi/mid/lo bf16 ----
__global__ void k_wsplit(const float* __restrict__ qkv_w, const float* __restrict__ proj_w,
                         u16* __restrict__ whi, u16* __restrict__ wmid, u16* __restrict__ wlo){
  int i = blockIdx.x*256 + threadIdx.x;
  float w = (i < O3*CC) ? qkv_w[i] : proj_w[i - O3*CC];
  u16 h = bf16_rn(w);          float r1 = w - bf16_to_f(h);
  u16 m = bf16_rn(r1);         float r2 = r1 - bf16_to_f(m);
  u16 l = bf16_rn(r2);
  whi[i]=h; wmid[i]=m; wlo[i]=l;
}

// ---- LIF scan on input x -> bf16 spikes ----
__global__ void k_lif_x(const float* __restrict__ x, const float* __restrict__ w,
                        float* __restrict__ vin, u16* __restrict__ s0, int t0, int tc){
  int g = blockIdx.x*256 + threadIdx.x;
  float sg = sigm(w[0]);
  float v = (t0==0) ? 0.f : vin[g];
  for (int tt=0; tt<tc; ++tt){
    float sp = lif_step(x[(size_t)(t0+tt)*PT + g], v, sg);
    s0[(size_t)tt*PT + g] = (sp!=0.f) ? 0x3F80 : 0;
  }
  vin[g] = v;
}

// ---- C[M,ON] = A(bf16 0/1)*W^T + bias; fused per-block BN partial stats ----
// MT = rows per block (256 or 128). Partials: psum/psq[mb][seg][o], seg = row
// beyond the (tt_base+1)*1568 boundary (a tile crosses <=1 boundary).
template<int ON, int MT>
__global__ __launch_bounds__(256, 2)
void k_gemm_mfma(const u16* __restrict__ A, const u16* __restrict__ Wh,
                 const u16* __restrict__ Wm, const u16* __restrict__ Wl,
                 const float* __restrict__ bias, float* __restrict__ Cm,
                 double* __restrict__ psum, double* __restrict__ psq, int M){
  constexpr int MTn = MT/32;           // mt count per wave-half (8 or 4)
  __shared__ __align__(16) u16 Al[MT][64];
  __shared__ __align__(16) u16 Bh[128][64];
  __shared__ __align__(16) u16 Bm[128][64];
  __shared__ __align__(16) u16 Bl[128][64];
  const int nON = ON/128;
  int nwg = gridDim.x;
  int bid = blockIdx.x;
  int q = nwg >> 3, r = nwg & 7;
  int xcd = bid & 7, idx = bid >> 3;
  int wgid = (xcd < r ? xcd*(q+1) : r*(q+1) + (xcd-r)*q) + idx;
  int mb = wgid / nON, ob = wgid - mb*nON;
  int m0 = mb*MT, o0 = ob*128;

  int tid = threadIdx.x;
  int w = tid>>6, lane = tid&63;
  int wm = (w&1)*(MT/2), wn = (w>>1)*64;
  int r16 = lane&15, kg = lane>>4;
  int lrowB = w*32 + (lane>>3);
  int lrowA = w*(MT/4) + (lane>>3);
  int lslot = lane&7;
  f32x4 acc[MTn][4] = {};
  for (int k0=0;k0<512;k0+=64){
    #pragma unroll
    for (int i=0;i<MT/32;++i){
      int row = lrowA + i*8;
      int gslot = lslot ^ (row&7);
      int gr = m0+row; if (gr>=M) gr=M-1;
      gld_lds16(&A[(size_t)gr*512 + k0 + gslot*8], &Al[w*(MT/4)+i*8][0]);
    }
    #pragma unroll
    for (int i=0;i<4;++i){
      int row = lrowB + i*8;
      int gslot = lslot ^ (row&7);
      gld_lds16(&Wh[(size_t)(o0+row)*512 + k0 + gslot*8], &Bh[w*32+i*8][0]);
      gld_lds16(&Wm[(size_t)(o0+row)*512 + k0 + gslot*8], &Bm[w*32+i*8][0]);
      gld_lds16(&Wl[(size_t)(o0+row)*512 + k0 + gslot*8], &Bl[w*32+i*8][0]);
    }
    __syncthreads();
    #pragma unroll
    for (int s=0;s<2;++s){
      short8 bh[4], bm[4], bl[4];
      #pragma unroll
      for (int nt=0;nt<4;++nt){
        int rr = wn + nt*16 + r16;
        int sl = ((s*4+kg)^(rr&7))*8;
        bh[nt] = *(const short8*)&Bh[rr][sl];
        bm[nt] = *(const short8*)&Bm[rr][sl];
        bl[nt] = *(const short8*)&Bl[rr][sl];
      }
      #pragma unroll
      for (int mt=0;mt<MTn;++mt){
        int rr = wm + mt*16 + r16;
        short8 af = *(const short8*)&Al[rr][((s*4+kg)^(rr&7))*8];
        #pragma unroll
        for (int nt=0;nt<4;++nt){
          acc[mt][nt] = __builtin_amdgcn_mfma_f32_16x16x32_bf16(af, bh[nt], acc[mt][nt],0,0,0);
          acc[mt][nt] = __builtin_amdgcn_mfma_f32_16x16x32_bf16(af, bm[nt], acc[mt][nt],0,0,0);
          acc[mt][nt] = __builtin_amdgcn_mfma_f32_16x16x32_bf16(af, bl[nt], acc[mt][nt],0,0,0);
        }
      }
    }
    __syncthreads();
  }
  // epilogue: C-write + fp64 column partial stats (value == stored value)
  int bseg = (m0/1568 + 1)*1568;
  double ssm[4][2] = {}, ssq2[4][2] = {};
  #pragma unroll
  for (int nt=0; nt<4; ++nt){
    int o = o0 + wn + nt*16 + r16;
    float bs = bias[o];
    #pragma unroll
    for (int mt=0; mt<MTn; ++mt){
      #pragma unroll
      for (int i=0;i<4;++i){
        int m = m0 + wm + mt*16 + kg*4 + i;
        if (m < M){
          float val = acc[mt][nt][i] + bs;
          Cm[(size_t)m*ON + o] = val;
          int sg = (m >= bseg) ? 1 : 0;
          ssm[nt][sg]  += (double)val;
          ssq2[nt][sg] += (double)val*(double)val;
        }
      }
    }
  }
  // reduce over kg (xor 16, 32), then combine wave m-halves via LDS
  #pragma unroll
  for (int nt=0;nt<4;++nt)
    #pragma unroll
    for (int sg=0;sg<2;++sg){
      ssm[nt][sg]  += __shfl_xor(ssm[nt][sg], 16);
      ssm[nt][sg]  += __shfl_xor(ssm[nt][sg], 32);
      ssq2[nt][sg] += __shfl_xor(ssq2[nt][sg], 16);
      ssq2[nt][sg] += __shfl_xor(ssq2[nt][sg], 32);
    }
  double* statd = (double*)&Al[0][0];   // 8KB, reuse (all waves past final barrier)
  if (lane < 16){
    #pragma unroll
    for (int nt=0;nt<4;++nt)
      #pragma unroll
      for (int sg=0;sg<2;++sg){
        int bi = (((w*4+nt)*16 + r16)*2 + sg)*2;
        statd[bi+0] = ssm[nt][sg];
        statd[bi+1] = ssq2[nt][sg];
      }
  }
  __syncthreads();
  {
    int sg = tid & 1, ol = tid >> 1;          // ol = 0..127
    int nh = ol>>6, ntv = (ol&63)>>4, rv = ol&15;
    int i0 = ((((2*nh+0)*4+ntv)*16 + rv)*2 + sg)*2;
    int i1 = ((((2*nh+1)*4+ntv)*16 + rv)*2 + sg)*2;
    size_t pi = ((size_t)mb*2 + sg)*ON + o0 + ol;
    psum[pi] = statd[i0+0] + statd[i1+0];
    psq [pi] = statd[i0+1] + statd[i1+1];
  }
}

// ---- fold per-block partials -> mean/rstd (deterministic, fp64) ----
template<int O, int MT>
__global__ void k_stat_fold(const double* __restrict__ psum, const double* __restrict__ psq,
                            float* __restrict__ mean, float* __restrict__ rstd,
                            int nmb, int total){
  int i = blockIdx.x*256 + threadIdx.x;
  if (i >= total) return;
  int tt = i / O, o = i - tt*O;
  double s=0.0, qq=0.0;
  for (int mb=0; mb<nmb; ++mb){
    int tb = (mb*MT)/1568;
    int sg = tt - tb;
    if (sg==0 || sg==1){
      size_t pi = ((size_t)mb*2 + sg)*O + o;
      s += psum[pi]; qq += psq[pi];
    }
  }
  double m = s*(1.0/BN);
  double var = qq*(1.0/BN) - m*m;
  mean[i] = (float)m;
  rstd[i] = (float)(1.0/sqrt(var+1e-5));
}

// ---- BN1 + LIF scan q/k/v -> bf16 spikes [tt,b,h,n,d] ----
__global__ void k_lif_qkv(const float* __restrict__ qkv, const float* __restrict__ mean,
                          const float* __restrict__ rstd, const float* __restrict__ g1,
                          const float* __restrict__ b1,
                          const float* __restrict__ wq, const float* __restrict__ wk,
                          const float* __restrict__ wv,
                          float* __restrict__ vq, float* __restrict__ vk, float* __restrict__ vv,
                          u16* __restrict__ qs, u16* __restrict__ ks,
                          u16* __restrict__ vs, int t0, int tc){
  int g = blockIdx.x*256 + threadIdx.x;
  int j = blockIdx.y;
  int d = g & 63;
  int n = (g>>6) % NNQ;
  int h = (g/(NNQ*64)) & 7;
  int b = g/(NNQ*64*8);
  int o = j*CC + h*HD + d;
  const float* w = (j==0)? wq : (j==1)? wk : wv;
  float* st  = (j==0)? vq : (j==1)? vk : vv;
  u16* out = (j==0)? qs : (j==1)? ks : vs;
  float sg = sigm(w[0]);
  float v = (t0==0) ? 0.f : st[g];
  size_t row = (size_t)(b*NNQ + n)*O3 + o;
  for (int tt=0; tt<tc; ++tt){
    float xv = qkv[(size_t)tt*BN*O3 + row];
    int so = tt*O3 + o;
    int go = (t0+tt)*O3 + o;
    float xn = __fadd_rn(__fmul_rn(__fmul_rn(__fsub_rn(xv, mean[so]), rstd[so]),
                                   g1[go]), b1[go]);
    float sp = lif_step(xn, v, sg);
    out[(size_t)tt*PT + g] = (sp!=0.f) ? 0x3F80 : 0;
  }
  st[g] = v;
}

// ---- per (tt,b,h): kv = K^T V (MFMA), then attn = 0.125 * Q kv (MFMA) ----
__global__ __launch_bounds__(256)
void k_kvqv_mfma(const u16* __restrict__ ks, const u16* __restrict__ vs,
                 const u16* __restrict__ qs, float* __restrict__ attn){
  __shared__ __align__(16) u16 Kb[224][64];
  __shared__ __align__(16) u16 Vb[224][64];
  __shared__ __align__(16) u16 kvb[64][64];
  int blk = blockIdx.x;
  size_t base = (size_t)blk * (NNQ*HD);
  int tid = threadIdx.x, w = tid>>6, lane = tid&63;
  int r16 = lane&15, kg = lane>>4;
  for (int u=tid; u<224*8; u+=256){
    int row=u>>3, slot=u&7;
    float4 z = {0.f,0.f,0.f,0.f};
    float4 kd = z, vd = z;
    if (row < NNQ){
      kd = *(const float4*)&ks[base + (size_t)row*64 + slot*8];
      vd = *(const float4*)&vs[base + (size_t)row*64 + slot*8];
    }
    *(float4*)&Kb[row][slot*8] = kd;
    *(float4*)&Vb[row][slot*8] = vd;
  }
  __syncthreads();
  f32x4 acc[4] = {};
  int d0 = w*16;
  for (int n0=0;n0<224;n0+=32){
    short8 af;
    #pragma unroll
    for (int jj=0;jj<8;++jj) af[jj] = (short)Kb[n0+kg*8+jj][d0 + r16];
    #pragma unroll
    for (int nt=0;nt<4;++nt){
      short8 bf;
      #pragma unroll
      for (int jj=0;jj<8;++jj) bf[jj] = (short)Vb[n0+kg*8+jj][nt*16 + r16];
      acc[nt] = __builtin_amdgcn_mfma_f32_16x16x32_bf16(af, bf, acc[nt],0,0,0);
    }
  }
  #pragma unroll
  for (int nt=0;nt<4;++nt)
    #pragma unroll
    for (int i=0;i<4;++i)
      kvb[d0 + kg*4 + i][nt*16 + r16] = (u16)(__float_as_uint(acc[nt][i])>>16);
  __syncthreads();
  for (int u=tid; u<224*8; u+=256){
    int row=u>>3, slot=u&7;
    int sl = slot ^ (row&7);
    float4 qd = {0.f,0.f,0.f,0.f};
    if (row < NNQ) qd = *(const float4*)&qs[base + (size_t)row*64 + slot*8];
    *(float4*)&Kb[row][sl*8] = qd;
  }
  __syncthreads();
  short8 bkv[2][4];
  #pragma unroll
  for (int s=0;s<2;++s)
    #pragma unroll
    for (int nt=0;nt<4;++nt){
      short8 bf;
      #pragma unroll
      for (int jj=0;jj<8;++jj) bf[jj] = (short)kvb[s*32 + kg*8 + jj][nt*16 + r16];
      bkv[s][nt] = bf;
    }
  for (int mt=w; mt<13; mt+=4){
    f32x4 a2[4] = {};
    short8 qa[2];
    #pragma unroll
    for (int s=0;s<2;++s){
      int rr = mt*16 + r16;
      qa[s] = *(const short8*)&Kb[rr][(((s*4+kg)^(rr&7)))*8];
    }
    #pragma unroll
    for (int s=0;s<2;++s)
      #pragma unroll
      for (int nt=0;nt<4;++nt)
        a2[nt] = __builtin_amdgcn_mfma_f32_16x16x32_bf16(qa[s], bkv[s][nt], a2[nt],0,0,0);
    #pragma unroll
    for (int nt=0;nt<4;++nt){
      int e = nt*16 + r16;
      #pragma unroll
      for (int i=0;i<4;++i){
        int n = mt*16 + kg*4 + i;
        if (n < NNQ) attn[base + (size_t)n*64 + e] = a2[nt][i]*0.125f;
      }
    }
  }
}

// ---- LIF scan on attention out -> bf16 spikes [tt,(b,n),C] ----
__global__ void k_lif_attn(const float* __restrict__ ain, const float* __restrict__ w,
                           float* __restrict__ vo, u16* __restrict__ sp, int t0, int tc){
  int g = blockIdx.x*256 + threadIdx.x;
  int e = g & 63;
  int n = (g>>6) % NNQ;
  int h = (g/(NNQ*64)) & 7;
  int b = g/(NNQ*64*8);
  size_t dst = (size_t)(b*NNQ + n)*CC + h*HD + e;
  float sg = sigm(w[0]);
  float v = (t0==0) ? 0.f : vo[g];
  for (int tt=0; tt<tc; ++tt){
    float s = lif_step(ain[(size_t)tt*PT + g], v, sg);
    sp[(size_t)tt*PT + dst] = (s!=0.f) ? 0x3F80 : 0;
  }
  vo[g] = v;
}

// ---- BN2 apply (vectorized, np-rounded) ----
__global__ void k_bn2_apply(const float* __restrict__ X, const float* __restrict__ mean,
                            const float* __restrict__ rstd, const float* __restrict__ g2,
                            const float* __restrict__ b2, float* __restrict__ Y, int t0){
  size_t idx = ((size_t)blockIdx.x*256 + threadIdx.x)*4;
  int tt = (int)(idx / PT);
  size_t off = idx - (size_t)tt*PT;
  int c = (int)(off & (CC-1));
  float4 xv = *(const float4*)&X[idx];
  float4 mv = *(const float4*)&mean[tt*CC + c];
  float4 rv = *(const float4*)&rstd[tt*CC + c];
  float4 gv = *(const float4*)&g2[(t0+tt)*CC + c];
  float4 bv = *(const float4*)&b2[(t0+tt)*CC + c];
  float4 yv;
  yv.x = __fadd_rn(__fmul_rn(__fmul_rn(__fsub_rn(xv.x, mv.x), rv.x), gv.x), bv.x);
  yv.y = __fadd_rn(__fmul_rn(__fmul_rn(__fsub_rn(xv.y, mv.y), rv.y), gv.y), bv.y);
  yv.z = __fadd_rn(__fmul_rn(__fmul_rn(__fsub_rn(xv.z, mv.z), rv.z), gv.z), bv.z);
  yv.w = __fadd_rn(__fmul_rn(__fmul_rn(__fsub_rn(xv.w, mv.w), rv.w), gv.w), bv.w);
  *(float4*)&Y[(size_t)(t0+tt)*PT + off] = yv;
}

extern "C" void kernel_launch(void* const* d_in, const int* in_sizes, int n_in,
                              void* d_out, int out_size, void* d_ws, size_t ws_size,
                              hipStream_t stream){
  const float* x      = (const float*)d_in[0];
  const float* qkv_w  = (const float*)d_in[1];
  const float* qkv_b  = (const float*)d_in[2];
  const float* bn1_g  = (const float*)d_in[3];
  const float* bn1_b  = (const float*)d_in[4];
  const float* proj_w = (const float*)d_in[5];
  const float* proj_b = (const float*)d_in[6];
  const float* bn2_g  = (const float*)d_in[7];
  const float* bn2_b  = (const float*)d_in[8];
  const float* w_in   = (const float*)d_in[9];
  const float* w_q    = (const float*)d_in[10];
  const float* w_k    = (const float*)d_in[11];
  const float* w_v    = (const float*)d_in[12];
  const float* w_proj = (const float*)d_in[13];
  float* outp = (float*)d_out;

  auto need = [](int tc)->size_t{
    int nmb1 = (tc*BN + 255)/256;
    int nmb2 = (tc*BN + 127)/128;
    return 4ull*5*PT + 4ull*tc*O3*2 + 4ull*tc*CC*2
         + 16ull*nmb1*2*O3 + 16ull*nmb2*2*CC
         + 6ull*WTOT
         + 10ull*tc*PT
         + 4ull*tc*BN*O3;
  };
  int TC = 16;
  while (TC > 1 && need(TC) > ws_size) TC >>= 1;
  int nmb1 = (TC*BN + 255)/256;
  int nmb2 = (TC*BN + 127)/128;

  char* p = (char*)d_ws;
  float* vin = (float*)p; p += 4ull*PT;
  float* vq  = (float*)p; p += 4ull*PT;
  float* vk  = (float*)p; p += 4ull*PT;
  float* vv  = (float*)p; p += 4ull*PT;
  float* vo  = (float*)p; p += 4ull*PT;
  float* mean1 = (float*)p; p += 4ull*TC*O3;
  float* rstd1 = (float*)p; p += 4ull*TC*O3;
  float* mean2 = (float*)p; p += 4ull*TC*CC;
  float* rstd2 = (float*)p; p += 4ull*TC*CC;
  double* p1sum = (double*)p; p += 8ull*nmb1*2*O3;
  double* p1sq  = (double*)p; p += 8ull*nmb1*2*O3;
  double* p2sum = (double*)p; p += 8ull*nmb2*2*CC;
  double* p2sq  = (double*)p; p += 8ull*nmb2*2*CC;
  u16* whi  = (u16*)p; p += 2ull*WTOT;
  u16* wmid = (u16*)p; p += 2ull*WTOT;
  u16* wlo  = (u16*)p; p += 2ull*WTOT;
  u16* s0    = (u16*)p; p += 2ull*TC*PT;
  u16* qsb   = (u16*)p; p += 2ull*TC*PT;
  u16* ksb   = (u16*)p; p += 2ull*TC*PT;
  u16* vsb   = (u16*)p; p += 2ull*TC*PT;
  u16* sproj = (u16*)p; p += 2ull*TC*PT;
  float* qkv_all = (float*)p;                 // tc*BN*O3 floats
  float* attn    = qkv_all;                   // tc*PT (overlaps dead qkv_all)
  float* projo   = qkv_all + (size_t)TC*PT;   // tc*PT

  k_wsplit<<<WTOT/256, 256, 0, stream>>>(qkv_w, proj_w, whi, wmid, wlo);

  for (int t0=0; t0<TT; t0+=TC){
    int M = TC*BN;
    k_lif_x<<<PT/256, 256, 0, stream>>>(x, w_in, vin, s0, t0, TC);

    k_gemm_mfma<O3,256><<<nmb1*(O3/128), 256, 0, stream>>>(
        s0, whi, wmid, wlo, qkv_b, qkv_all, p1sum, p1sq, M);

    k_stat_fold<O3,256><<<(TC*O3+255)/256, 256, 0, stream>>>(
        p1sum, p1sq, mean1, rstd1, nmb1, TC*O3);

    k_lif_qkv<<<dim3(PT/256, 3), 256, 0, stream>>>(qkv_all, mean1, rstd1, bn1_g, bn1_b,
                                                   w_q, w_k, w_v, vq, vk, vv,
                                                   qsb, ksb, vsb, t0, TC);

    k_kvqv_mfma<<<TC*BB*HH, 256, 0, stream>>>(ksb, vsb, qsb, attn);

    k_lif_attn<<<PT/256, 256, 0, stream>>>(attn, w_proj, vo, sproj, t0, TC);

    k_gemm_mfma<CC,128><<<nmb2*(CC/128), 256, 0, stream>>>(
        sproj, whi + (size_t)O3*CC, wmid + (size_t)O3*CC, wlo + (size_t)O3*CC,
        proj_b, projo, p2sum, p2sq, M);

    k_stat_fold<CC,128><<<(TC*CC+255)/256, 256, 0, stream>>>(
        p2sum, p2sq, mean2, rstd2, nmb2, TC*CC);

    k_bn2_apply<<<(TC*(size_t)PT)/1024, 256, 0, stream>>>(projo, mean2, rstd2,
                                                          bn2_g, bn2_b, outp, t0);
  }
}